// Round 1
// baseline (998.176 us; speedup 1.0000x reference)
//
#include <hip/hip_runtime.h>

// ---------------- LDS layout ----------------
// X buffer: 12320 floats. Holds x rows (pad 12 + 4-word skew per 128-row group)
// during P0-P1, then reused as scratch.
// S buffer: 6176 floats. Holds S0/shot rows (pad 12 + 4-word skew per 64 rows).
// ST buffer: 2560 ushort. state in bf16 (only used for tanh diffs).
#define XOFF(c)  ((c)*12 + (((c)>>7)<<2))
#define SOFF(c)  ((c)*12 + (((c)>>6)<<2))

#define QKP  132          // padded row stride for q/k transposed tiles
#define QST  0            // qsT [10][132]   (phase 4-5a)
#define KST  1320         // ksT [10][132]
#define QDT  2640         // qdT [10][132]   (phase 5a-5b)
#define KDT  3960         // kdT [10][132]
#define Y0O  2688         // Y0/ys [256][10] f32 (phase 6-8; QDT/KDT dead by then)
#define SCN  0            // scene [256][7]  (phase 8-9; qsT dead)
#define VVO  1792         // v [128][7]      (phase 9-10)
#define RED4 5280         // qk_d partials [128][2][2][10] (phase 4-5a)
#define RED2 10400        // tanh partials [136] (phase 2)
#define ASTA 10544        // A_sta [10][10]  (phase 2-3)
#define BSO  10644        // Bs/As [10][10]  (phase 5a-7a)
#define BDO  10744        // Bd/Ad [10][10]  (phase 5b-7b)
#define P0O  10844        // P0 [7][10]      (phase 7a-7b)
#define PRD  10914        // P partials [280] (phase 6-7a)
#define TTO  11194        // T [7][10]       (phase 7b-8)
#define MUO  11264        // mu [7]
#define LVO  11271        // logvar [7]
#define SRO  11278        // score reduce [7]

#define RSQRT128 0.08838834764831843f

static __device__ __forceinline__ float bf16u(unsigned short u) {
    return __uint_as_float(((unsigned int)u) << 16);
}
static __device__ __forceinline__ unsigned short bf16p(float f) {
    unsigned int b = __float_as_uint(f);
    b += 0x7fffu + ((b >> 16) & 1u);          // round-to-nearest-even
    return (unsigned short)(b >> 16);
}
static __device__ __forceinline__ float fast_tanh(float v) {
    return 1.0f - 2.0f / (__expf(2.0f * v) + 1.0f);
}
static __device__ __forceinline__ void softmax10(float* row) {
    float mx = row[0];
#pragma unroll
    for (int i = 1; i < 10; ++i) mx = fmaxf(mx, row[i]);
    float e[10]; float sm = 0.0f;
#pragma unroll
    for (int i = 0; i < 10; ++i) { e[i] = __expf(row[i] - mx); sm += e[i]; }
    const float inv = 1.0f / sm;
#pragma unroll
    for (int i = 0; i < 10; ++i) row[i] = e[i] * inv;
}

__global__ __launch_bounds__(256, 2)
void hgcn_fused(const float* __restrict__ x,      const float* __restrict__ esp,
                const float* __restrict__ w_state,const float* __restrict__ b_state,
                const float* __restrict__ w_info, const float* __restrict__ b_info,
                const float* __restrict__ wq_s,   const float* __restrict__ wk_s,
                const float* __restrict__ C_s,    const float* __restrict__ alpha_s,
                const float* __restrict__ w_sagg, const float* __restrict__ b_sagg,
                const float* __restrict__ wq_d,   const float* __restrict__ wk_d,
                const float* __restrict__ C_d,    const float* __restrict__ alpha_d,
                const float* __restrict__ w_dagg, const float* __restrict__ b_dagg,
                const float* __restrict__ S_d,    const float* __restrict__ alpha_dif,
                const float* __restrict__ w_mot,  const float* __restrict__ b_mot,
                const float* __restrict__ w_mean, const float* __restrict__ b_mean,
                const float* __restrict__ w_logv, const float* __restrict__ b_logv,
                float* __restrict__ out, int B)
{
    __shared__ float X[12320];
    __shared__ float S[6176];
    __shared__ unsigned short ST[2560];

    const int tl = threadIdx.x;
    long b = blockIdx.x;
    if (b >= B) b = B - 1;

    const float aS  = alpha_s[0];
    const float aD  = alpha_d[0];
    const float aDf = alpha_dif[0];

    // ---- P0: stage x[b] (1024x10 f32) into LDS, padded + skewed rows ----
    {
        const float* xg = x + b * 10240;
#pragma unroll
        for (int k = 0; k < 10; ++k) {
            const int f = (tl << 2) + (k << 10);
            const float4 v4 = *(const float4*)(xg + f);
            const float vv[4] = {v4.x, v4.y, v4.z, v4.w};
#pragma unroll
            for (int j = 0; j < 4; ++j) {
                const int fe = f + j;
                const int c = fe / 10;
                const int n = fe - c * 10;
                X[XOFF(c) + n] = vv[j];
            }
        }
    }
    __syncthreads();

    // ---- P1: state = relu(Wst.x + b) -> bf16 LDS  (64 quad-threads)
    //          S0 = Winfo.x (no bias)  -> S          (128 quad-threads)
    if (tl < 64) {
        const int o0 = tl << 2;
        const int xb = (o0 >> 5) << 7;          // group * 128 (Cout/g = 32)
        float acc[4][10];
#pragma unroll
        for (int j = 0; j < 4; ++j)
#pragma unroll
            for (int n = 0; n < 10; ++n) acc[j][n] = 0.0f;
        for (int i4 = 0; i4 < 32; ++i4) {
            float w[4][4];
#pragma unroll
            for (int j = 0; j < 4; ++j) {
                const float4 w4 = *(const float4*)(w_state + (o0 + j) * 128 + (i4 << 2));
                w[j][0] = w4.x; w[j][1] = w4.y; w[j][2] = w4.z; w[j][3] = w4.w;
            }
#pragma unroll
            for (int ii = 0; ii < 4; ++ii) {
                const int c = xb + (i4 << 2) + ii;
                const float* xr = X + XOFF(c);
                const float4 xa = *(const float4*)(xr);
                const float4 xb4 = *(const float4*)(xr + 4);
                const float2 xc = *(const float2*)(xr + 8);
                const float xv[10] = {xa.x, xa.y, xa.z, xa.w,
                                      xb4.x, xb4.y, xb4.z, xb4.w, xc.x, xc.y};
#pragma unroll
                for (int j = 0; j < 4; ++j)
#pragma unroll
                    for (int n = 0; n < 10; ++n) acc[j][n] += xv[n] * w[j][ii];
            }
        }
#pragma unroll
        for (int j = 0; j < 4; ++j) {
            const float bb = b_state[o0 + j];
#pragma unroll
            for (int n = 0; n < 10; ++n)
                ST[(o0 + j) * 10 + n] = bf16p(fmaxf(acc[j][n] + bb, 0.0f));
        }
    } else if (tl < 192) {
        const int o0 = (tl - 64) << 2;
        const int xb = (o0 >> 6) << 7;          // group * 128 (Cout/g = 64)
        float acc[4][10];
#pragma unroll
        for (int j = 0; j < 4; ++j)
#pragma unroll
            for (int n = 0; n < 10; ++n) acc[j][n] = 0.0f;
        for (int i4 = 0; i4 < 32; ++i4) {
            float w[4][4];
#pragma unroll
            for (int j = 0; j < 4; ++j) {
                const float4 w4 = *(const float4*)(w_info + (o0 + j) * 128 + (i4 << 2));
                w[j][0] = w4.x; w[j][1] = w4.y; w[j][2] = w4.z; w[j][3] = w4.w;
            }
#pragma unroll
            for (int ii = 0; ii < 4; ++ii) {
                const int c = xb + (i4 << 2) + ii;
                const float* xr = X + XOFF(c);
                const float4 xa = *(const float4*)(xr);
                const float4 xb4 = *(const float4*)(xr + 4);
                const float2 xc = *(const float2*)(xr + 8);
                const float xv[10] = {xa.x, xa.y, xa.z, xa.w,
                                      xb4.x, xb4.y, xb4.z, xb4.w, xc.x, xc.y};
#pragma unroll
                for (int j = 0; j < 4; ++j)
#pragma unroll
                    for (int n = 0; n < 10; ++n) acc[j][n] += xv[n] * w[j][ii];
            }
        }
#pragma unroll
        for (int j = 0; j < 4; ++j) {
            float* sr = S + SOFF(o0 + j);
#pragma unroll
            for (int n = 0; n < 10; ++n) sr[n] = acc[j][n];
        }
    }
    __syncthreads();

    // ---- P2a: tanh partials over channel chunks; zero A_sta ----
    if (tl < 136) {
        const int p = tl >> 3, part = tl & 7;
        const int n = (p < 9) ? p : (p - 9);
        const int m = (p < 9) ? (p + 1) : (p - 9 + 2);
        const int c0 = part << 5;
        float s = 0.0f;
        for (int c = c0; c < c0 + 32; ++c)
            s += fast_tanh(bf16u(ST[c * 10 + n]) - bf16u(ST[c * 10 + m]));
        X[RED2 + tl] = s;
    } else if (tl < 236) {
        X[ASTA + (tl - 136)] = 0.0f;
    }
    __syncthreads();
    // ---- P2b: assemble A_sta (band |d|<=2; antisymmetric; diag = 1) ----
    if (tl < 17) {
        const int p = tl;
        float s = 0.0f;
#pragma unroll
        for (int j = 0; j < 8; ++j) s += X[RED2 + (p << 3) + j];
        s *= (1.0f / 256.0f);
        const int n = (p < 9) ? p : (p - 9);
        const int m = (p < 9) ? (p + 1) : (p - 9 + 2);
        X[ASTA + n * 10 + m] = s;
        X[ASTA + m * 10 + n] = -s;
    } else if (tl < 27) {
        const int n = tl - 17;
        X[ASTA + n * 10 + n] = 1.0f;
    }
    __syncthreads();

    // ---- P3: shot = relu(S0 . A_sta + b_info), in place on S ----
#pragma unroll
    for (int rep = 0; rep < 2; ++rep) {
        const int o = tl + (rep << 8);
        float* row = S + SOFF(o);
        float r[10];
#pragma unroll
        for (int n = 0; n < 10; ++n) r[n] = row[n];
        const float bi = b_info[o];
        float sh[10];
#pragma unroll
        for (int m = 0; m < 10; ++m) {
            float a = bi;
#pragma unroll
            for (int n = 0; n < 10; ++n) a += r[n] * X[ASTA + n * 10 + m];
            sh[m] = fmaxf(a, 0.0f);
        }
#pragma unroll
        for (int m = 0; m < 10; ++m) row[m] = sh[m];
    }
    __syncthreads();

    // ---- P4: q_s/k_s (grouped, K=64) and q_d/k_d partials (dense, K=512) ----
    {
        const int o = tl & 127;
        const float* wp = (tl < 128) ? wq_s : wk_s;
        float* dst = X + ((tl < 128) ? QST : KST);
        const int cb = (o >> 4) << 6;           // group*64 (Cout/g=16)
        float acc[10];
#pragma unroll
        for (int n = 0; n < 10; ++n) acc[n] = 0.0f;
        for (int i4 = 0; i4 < 16; ++i4) {
            const float4 w4 = *(const float4*)(wp + (o << 6) + (i4 << 2));
            const float w[4] = {w4.x, w4.y, w4.z, w4.w};
#pragma unroll
            for (int ii = 0; ii < 4; ++ii) {
                const int c = cb + (i4 << 2) + ii;
                const float* sr = S + SOFF(c);
                const float4 sa = *(const float4*)(sr);
                const float4 sb = *(const float4*)(sr + 4);
                const float2 sc2 = *(const float2*)(sr + 8);
                const float sv[10] = {sa.x, sa.y, sa.z, sa.w,
                                      sb.x, sb.y, sb.z, sb.w, sc2.x, sc2.y};
#pragma unroll
                for (int n = 0; n < 10; ++n) acc[n] += sv[n] * w[ii];
            }
        }
#pragma unroll
        for (int n = 0; n < 10; ++n) dst[n * QKP + o] = acc[n];
    }
    {
        const int opair = tl & 127;
        const int khalf = tl >> 7;
        const float* wbase = (opair < 64) ? (wq_d + ((opair << 1) * 512))
                                          : (wk_d + (((opair - 64) << 1) * 512));
        const int cb = khalf << 8;
        float acc0[10], acc1[10];
#pragma unroll
        for (int n = 0; n < 10; ++n) { acc0[n] = 0.0f; acc1[n] = 0.0f; }
        for (int i4 = 0; i4 < 64; ++i4) {
            const float4 wa = *(const float4*)(wbase + cb + (i4 << 2));
            const float4 wb = *(const float4*)(wbase + 512 + cb + (i4 << 2));
            const float w0[4] = {wa.x, wa.y, wa.z, wa.w};
            const float w1[4] = {wb.x, wb.y, wb.z, wb.w};
#pragma unroll
            for (int ii = 0; ii < 4; ++ii) {
                const int c = cb + (i4 << 2) + ii;
                const float* sr = S + SOFF(c);
                const float4 sa = *(const float4*)(sr);
                const float4 sb = *(const float4*)(sr + 4);
                const float2 sc2 = *(const float2*)(sr + 8);
                const float sv[10] = {sa.x, sa.y, sa.z, sa.w,
                                      sb.x, sb.y, sb.z, sb.w, sc2.x, sc2.y};
#pragma unroll
                for (int n = 0; n < 10; ++n) {
                    acc0[n] += sv[n] * w0[ii];
                    acc1[n] += sv[n] * w1[ii];
                }
            }
        }
        float* rp = X + RED4 + opair * 40 + khalf * 20;
#pragma unroll
        for (int n = 0; n < 10; ++n) { rp[n] = acc0[n]; rp[10 + n] = acc1[n]; }
    }
    __syncthreads();

    // ---- P5a: finalize qdT/kdT; Bs logits ----
    {
        const int o = tl;
        const int opair = o >> 1, oj = o & 1;
        const float* rp = X + RED4 + opair * 40 + oj * 10;
        float* dst = X + ((o < 128) ? QDT : KDT);
        const int oc = o & 127;
#pragma unroll
        for (int n = 0; n < 10; ++n) dst[n * QKP + oc] = rp[n] + rp[20 + n];
    }
    if (tl < 100) {
        const int n = tl / 10, m = tl - (tl / 10) * 10;
        const float* qr = X + QST + n * QKP;
        const float* kr = X + KST + m * QKP;
        float s = 0.0f;
#pragma unroll
        for (int c4 = 0; c4 < 32; ++c4) {
            const float4 q4 = *(const float4*)(qr + (c4 << 2));
            const float4 k4 = *(const float4*)(kr + (c4 << 2));
            s += q4.x * k4.x + q4.y * k4.y + q4.z * k4.z + q4.w * k4.w;
        }
        const int d = (n > m) ? (n - m) : (m - n);
        X[BSO + tl] = aS * (s * RSQRT128) + C_s[n * 10 + m] + ((d <= 3) ? 1.0f : 0.0f);
    }
    __syncthreads();

    // ---- P5b: Bd logits; softmax(As) ----
    if (tl < 100) {
        const int n = tl / 10, m = tl - (tl / 10) * 10;
        const float* qr = X + QDT + n * QKP;
        const float* kr = X + KDT + m * QKP;
        float s = 0.0f;
#pragma unroll
        for (int c4 = 0; c4 < 32; ++c4) {
            const float4 q4 = *(const float4*)(qr + (c4 << 2));
            const float4 k4 = *(const float4*)(kr + (c4 << 2));
            s += q4.x * k4.x + q4.y * k4.y + q4.z * k4.z + q4.w * k4.w;
        }
        const int d = (n > m) ? (n - m) : (m - n);
        X[BDO + tl] = aD * (s * RSQRT128) + C_d[n * 10 + m] + ((d <= 3) ? 1.0f : 0.0f);
    } else if (tl >= 128 && tl < 138) {
        softmax10(X + BSO + (tl - 128) * 10);
    }
    __syncthreads();

    // ---- P6: Y0 = gconv(shot, w_sagg) (no bias); P partials; softmax(Ad) ----
    {
        const int o = tl;
        const int cb = (o >> 5) << 6;           // group*64 (Cout/g=32)
        float acc[10];
#pragma unroll
        for (int n = 0; n < 10; ++n) acc[n] = 0.0f;
        for (int i4 = 0; i4 < 16; ++i4) {
            const float4 w4 = *(const float4*)(w_sagg + (o << 6) + (i4 << 2));
            const float w[4] = {w4.x, w4.y, w4.z, w4.w};
#pragma unroll
            for (int ii = 0; ii < 4; ++ii) {
                const int c = cb + (i4 << 2) + ii;
                const float* sr = S + SOFF(c);
                const float4 sa = *(const float4*)(sr);
                const float4 sb = *(const float4*)(sr + 4);
                const float2 sc2 = *(const float2*)(sr + 8);
                const float sv[10] = {sa.x, sa.y, sa.z, sa.w,
                                      sb.x, sb.y, sb.z, sb.w, sc2.x, sc2.y};
#pragma unroll
                for (int n = 0; n < 10; ++n) acc[n] += sv[n] * w[ii];
            }
        }
        float* yr = X + Y0O + o * 10;
#pragma unroll
        for (int n = 0; n < 10; ++n) yr[n] = acc[n];
    }
    for (int tt = tl; tt < 280; tt += 256) {
        const int o = tt / 40;
        const int rem = tt - o * 40;
        const int n = rem >> 2, part = rem & 3;
        const float* wr = w_dagg + o * 512 + (part << 7);
        float s = 0.0f;
        for (int c = 0; c < 128; ++c) s += wr[c] * S[SOFF((part << 7) + c) + n];
        X[PRD + tt] = s;
    }
    if (tl >= 128 && tl < 138) softmax10(X + BDO + (tl - 128) * 10);
    __syncthreads();

    // ---- P7a: ys = relu(Y0 . As + b_sagg) in place; finalize P0 ----
    {
        const int o = tl;
        float* yr = X + Y0O + o * 10;
        float r[10];
#pragma unroll
        for (int n = 0; n < 10; ++n) r[n] = yr[n];
        const float bs = b_sagg[o];
        float ys[10];
#pragma unroll
        for (int m = 0; m < 10; ++m) {
            float a = bs;
#pragma unroll
            for (int n = 0; n < 10; ++n) a += r[n] * X[BSO + n * 10 + m];
            ys[m] = fmaxf(a, 0.0f);
        }
#pragma unroll
        for (int m = 0; m < 10; ++m) yr[m] = ys[m];
    }
    if (tl < 70) {
        const int o = tl / 10, n = tl - (tl / 10) * 10;
        const float* pr = X + PRD + o * 40 + (n << 2);
        X[P0O + o * 10 + n] = pr[0] + pr[1] + pr[2] + pr[3];
    }
    __syncthreads();

    // ---- P7b: T = S_d + alpha_diff * relu(P0 . Ad + b_dagg) ----
    if (tl < 70) {
        const int o = tl / 10, m = tl - (tl / 10) * 10;
        float a = b_dagg[o];
#pragma unroll
        for (int n = 0; n < 10; ++n) a += X[P0O + o * 10 + n] * X[BDO + n * 10 + m];
        X[TTO + tl] = S_d[o * 10 + m] + aDf * fmaxf(a, 0.0f);
    }
    __syncthreads();

    // ---- P8: scene[c][m] = sum_n ys[c][n] * T[m][n] ----
    {
        const int o = tl;
        const float* yr = X + Y0O + o * 10;
        float r[10];
#pragma unroll
        for (int n = 0; n < 10; ++n) r[n] = yr[n];
#pragma unroll
        for (int m = 0; m < 7; ++m) {
            float a = 0.0f;
#pragma unroll
            for (int n = 0; n < 10; ++n) a += r[n] * X[TTO + m * 10 + n];
            X[SCN + o * 7 + m] = a;
        }
    }
    __syncthreads();

    // ---- P9: v = relu(gconv(scene, w_mot, b_mot, g=8)) ----
    if (tl < 128) {
        const int o = tl;
        const int cb = (o >> 4) << 5;           // group*32 (Cout/g=16)
        float wr[32];
#pragma unroll
        for (int i4 = 0; i4 < 8; ++i4) {
            const float4 w4 = *(const float4*)(w_mot + (o << 5) + (i4 << 2));
            wr[i4 * 4 + 0] = w4.x; wr[i4 * 4 + 1] = w4.y;
            wr[i4 * 4 + 2] = w4.z; wr[i4 * 4 + 3] = w4.w;
        }
        const float bm = b_mot[o];
#pragma unroll
        for (int s = 0; s < 7; ++s) {
            float a = bm;
#pragma unroll
            for (int i = 0; i < 32; ++i) a += wr[i] * X[SCN + (cb + i) * 7 + s];
            X[VVO + o * 7 + s] = fmaxf(a, 0.0f);
        }
    }
    __syncthreads();

    // ---- P10: mu / logvar heads ----
    if (tl < 14) {
        const int hd = tl / 7;
        const int s = tl - hd * 7;
        const float* wp = hd ? w_logv : w_mean;
        float a = hd ? b_logv[0] : b_mean[0];
        for (int c = 0; c < 128; ++c) a += X[VVO + c * 7 + s] * wp[c];
        X[(hd ? LVO : MUO) + s] = a;
    }
    __syncthreads();

    // ---- P11: reparameterize + writes ----
    if (tl < 7) {
        const int s = tl;
        const float muv  = X[MUO + s];
        const float stdv = __expf(0.5f * X[LVO + s]);
        const float sc = muv + stdv * esp[b * 7 + s];
        X[SRO + s] = sc;
        out[(long)B + b * 7 + s]     = muv;
        out[(long)B * 8 + b * 7 + s] = stdv;
    }
    __syncthreads();
    if (tl == 0) {
        float s = 0.0f;
#pragma unroll
        for (int j = 0; j < 7; ++j) s += X[SRO + j];
        out[b] = s;                              // mean(-1) * NS == sum
    }
}

extern "C" void kernel_launch(void* const* d_in, const int* in_sizes, int n_in,
                              void* d_out, int out_size, void* d_ws, size_t ws_size,
                              hipStream_t stream) {
    (void)n_in; (void)out_size; (void)d_ws; (void)ws_size;
    const int B = in_sizes[0] / 10240;           // x is [B,1024,10]
    if (B <= 0) return;
    dim3 grid(B), block(256);
    hgcn_fused<<<grid, block, 0, stream>>>(
        (const float*)d_in[0],  (const float*)d_in[1],  (const float*)d_in[2],
        (const float*)d_in[3],  (const float*)d_in[4],  (const float*)d_in[5],
        (const float*)d_in[6],  (const float*)d_in[7],  (const float*)d_in[8],
        (const float*)d_in[9],  (const float*)d_in[10], (const float*)d_in[11],
        (const float*)d_in[12], (const float*)d_in[13], (const float*)d_in[14],
        (const float*)d_in[15], (const float*)d_in[16], (const float*)d_in[17],
        (const float*)d_in[18], (const float*)d_in[19], (const float*)d_in[20],
        (const float*)d_in[21], (const float*)d_in[22], (const float*)d_in[23],
        (const float*)d_in[24], (const float*)d_in[25],
        (float*)d_out, B);
}

// Round 3
// 585.207 us; speedup vs baseline: 1.7057x; 1.7057x over previous
//
#include <hip/hip_runtime.h>

// f16 vector types
typedef _Float16 h2 __attribute__((ext_vector_type(2)));
typedef __fp16   h2n __attribute__((ext_vector_type(2)));   // builtin's native type
struct alignas(16) H8 { h2 a, b, c, d; };          // 8 halves = one b128
struct alignas(8)  U2 { unsigned int x, y; };      // one b64

static __device__ __forceinline__ float dot2(h2 a, h2 b, float c) {
#if __has_builtin(__builtin_amdgcn_fdot2)
    return __builtin_amdgcn_fdot2(__builtin_bit_cast(h2n, a),
                                  __builtin_bit_cast(h2n, b), c, false);
#else
    return c + (float)a[0] * (float)b[0] + (float)a[1] * (float)b[1];
#endif
}
static __device__ __forceinline__ h2 pk(float a, float b) {
#if __has_builtin(__builtin_amdgcn_cvt_pkrtz)
    return __builtin_bit_cast(h2, __builtin_amdgcn_cvt_pkrtz(a, b));
#else
    h2 r; r[0] = (_Float16)a; r[1] = (_Float16)b; return r;
#endif
}
static __device__ __forceinline__ unsigned short f16b(float v) {
    return __builtin_bit_cast(unsigned short, (_Float16)v);
}
static __device__ __forceinline__ float fast_tanh(float v) {
    return 1.0f - 2.0f / (__expf(2.0f * v) + 1.0f);
}
static __device__ __forceinline__ void softmax10(float* row) {
    float mx = row[0];
#pragma unroll
    for (int i = 1; i < 10; ++i) mx = fmaxf(mx, row[i]);
    float e[10]; float sm = 0.0f;
#pragma unroll
    for (int i = 0; i < 10; ++i) { e[i] = __expf(row[i] - mx); sm += e[i]; }
    const float inv = 1.0f / sm;
#pragma unroll
    for (int i = 0; i < 10; ++i) row[i] = e[i] * inv;
}

// LDS layouts (ushort offsets). Node-major f16 with per-group skew.
#define XO(n,c)  ((n)*1152 + (c) + (((c)>>6)<<3))   // x   [10][1024+skew]
#define SO(n,c)  ((n)*576  + (c) + (((c)>>6)<<3))   // shot[10][512+skew]
#define STO(n,c) ((n)*288  + (c) + (((c)>>5)<<2))   // state[10][256+skew] (aliases SB)

// qT tiles (f16) inside XB scratch (x dead after P1b). Stride 136.
#define QST 0
#define KST 1360
#define QDT 2720
#define KDT 4080
// f32 views into XB scratch (XF = (float*)XB, 5760 f32 slots)
#define Y0F_BASE 2752      // Y0/ys [256][11]  (P6..P8)
#define SCN_BASE 0         // scene [256][7]   (P8..P9)
#define VV_BASE  1792      // v     [128][7]   (P9..P10)
// SMf small f32 buffer
#define RED2 0
#define ASTA 136
#define BSO  236
#define BDO  336
#define PRD  436
#define P0O  716
#define TTO  786
#define MUO  856
#define LVO  863
#define SRO  870

#define RSQRT128 0.08838834764831843f

__global__ __launch_bounds__(256, 4)
void hgcn_fused(const float* __restrict__ x,      const float* __restrict__ esp,
                const float* __restrict__ w_state,const float* __restrict__ b_state,
                const float* __restrict__ w_info, const float* __restrict__ b_info,
                const float* __restrict__ wq_s,   const float* __restrict__ wk_s,
                const float* __restrict__ C_s,    const float* __restrict__ alpha_s,
                const float* __restrict__ w_sagg, const float* __restrict__ b_sagg,
                const float* __restrict__ wq_d,   const float* __restrict__ wk_d,
                const float* __restrict__ C_d,    const float* __restrict__ alpha_d,
                const float* __restrict__ w_dagg, const float* __restrict__ b_dagg,
                const float* __restrict__ S_d,    const float* __restrict__ alpha_dif,
                const float* __restrict__ w_mot,  const float* __restrict__ b_mot,
                const float* __restrict__ w_mean, const float* __restrict__ b_mean,
                const float* __restrict__ w_logv, const float* __restrict__ b_logv,
                float* __restrict__ out, int B)
{
    __shared__ __align__(16) unsigned short XB[11520];   // 23040 B
    __shared__ __align__(16) unsigned short SB[5760];    // 11520 B
    __shared__ __align__(16) float SMf[904];             //  3616 B
    float* const XF = (float*)XB;

    const int tl = threadIdx.x;
    const long b = blockIdx.x;

    const float aS  = alpha_s[0];
    const float aD  = alpha_d[0];
    const float aDf = alpha_dif[0];

    // ---- P0: stage x[b] -> XB f16 node-major. Thread owns channels 4tl..4tl+3.
    {
        const float* xg = x + b * 10240 + tl * 40;
        float v[40];
#pragma unroll
        for (int k = 0; k < 10; ++k) {
            const float4 t = *(const float4*)(xg + (k << 2));
            v[k * 4 + 0] = t.x; v[k * 4 + 1] = t.y; v[k * 4 + 2] = t.z; v[k * 4 + 3] = t.w;
        }
#pragma unroll
        for (int n = 0; n < 10; ++n) {
            U2 u;
            u.x = __builtin_bit_cast(unsigned int, pk(v[n], v[10 + n]));
            u.y = __builtin_bit_cast(unsigned int, pk(v[20 + n], v[30 + n]));
            *(U2*)(XB + XO(n, tl << 2)) = u;
        }
    }
    __syncthreads();

    // ---- P1a: state = relu(W_state.x + b). One output per thread -> STO (in SB).
    {
        const int o = tl, g = o >> 5, cb = g << 7;
        const float* wr = w_state + o * 128;
        float acc[10];
#pragma unroll
        for (int n = 0; n < 10; ++n) acc[n] = 0.0f;
        for (int c8 = 0; c8 < 16; ++c8) {
            const float4 wa = *(const float4*)(wr + (c8 << 3));
            const float4 wb = *(const float4*)(wr + (c8 << 3) + 4);
            const h2 w0 = pk(wa.x, wa.y), w1 = pk(wa.z, wa.w);
            const h2 w2 = pk(wb.x, wb.y), w3 = pk(wb.z, wb.w);
#pragma unroll
            for (int n = 0; n < 10; ++n) {
                const H8 xv = *(const H8*)(XB + XO(n, cb + (c8 << 3)));
                acc[n] = dot2(xv.d, w3, dot2(xv.c, w2, dot2(xv.b, w1, dot2(xv.a, w0, acc[n]))));
            }
        }
        const float bb = b_state[o];
#pragma unroll
        for (int n = 0; n < 10; ++n)
            SB[STO(n, o)] = f16b(fmaxf(acc[n] + bb, 0.0f));
    }
    __syncthreads();

    // ---- P2a: tanh partials (136 threads); zero A_sta (100 threads) ----
    if (tl < 136) {
        const int p = tl >> 3, part = tl & 7;
        const int n = (p < 9) ? p : (p - 9);
        const int m = (p < 9) ? (p + 1) : (p - 9 + 2);
        const int c0 = part << 5;
        float s = 0.0f;
#pragma unroll
        for (int i = 0; i < 8; ++i) {
            const U2 un = *(const U2*)(SB + STO(n, c0 + (i << 2)));
            const U2 um = *(const U2*)(SB + STO(m, c0 + (i << 2)));
            const h2 n0 = __builtin_bit_cast(h2, un.x), n1 = __builtin_bit_cast(h2, un.y);
            const h2 m0 = __builtin_bit_cast(h2, um.x), m1 = __builtin_bit_cast(h2, um.y);
            s += fast_tanh((float)n0[0] - (float)m0[0]);
            s += fast_tanh((float)n0[1] - (float)m0[1]);
            s += fast_tanh((float)n1[0] - (float)m1[0]);
            s += fast_tanh((float)n1[1] - (float)m1[1]);
        }
        SMf[RED2 + tl] = s;
    } else if (tl < 236) {
        SMf[ASTA + (tl - 136)] = 0.0f;
    }
    __syncthreads();

    // ---- P1b: A_sta finalize (tiny) + info gconv S0 = W_info.x -> SB f16 ----
    if (tl < 17) {
        const int p = tl;
        float s = 0.0f;
#pragma unroll
        for (int j = 0; j < 8; ++j) s += SMf[RED2 + (p << 3) + j];
        s *= (1.0f / 256.0f);
        const int n = (p < 9) ? p : (p - 9);
        const int m = (p < 9) ? (p + 1) : (p - 9 + 2);
        SMf[ASTA + n * 10 + m] = s;
        SMf[ASTA + m * 10 + n] = -s;
    } else if (tl < 27) {
        const int n = tl - 17;
        SMf[ASTA + n * 10 + n] = 1.0f;
    }
    {
        const int g = tl >> 5;
        const int o = (g << 6) + (tl & 31);
        const int o2 = o + 32;
        const int cb = g << 7;
        const float* wr0 = w_info + o * 128;
        const float* wr1 = w_info + o2 * 128;
        float a0[10], a1[10];
#pragma unroll
        for (int n = 0; n < 10; ++n) { a0[n] = 0.0f; a1[n] = 0.0f; }
        for (int c8 = 0; c8 < 16; ++c8) {
            const float4 wa0 = *(const float4*)(wr0 + (c8 << 3));
            const float4 wb0 = *(const float4*)(wr0 + (c8 << 3) + 4);
            const float4 wa1 = *(const float4*)(wr1 + (c8 << 3));
            const float4 wb1 = *(const float4*)(wr1 + (c8 << 3) + 4);
            const h2 p00 = pk(wa0.x, wa0.y), p01 = pk(wa0.z, wa0.w);
            const h2 p02 = pk(wb0.x, wb0.y), p03 = pk(wb0.z, wb0.w);
            const h2 p10 = pk(wa1.x, wa1.y), p11 = pk(wa1.z, wa1.w);
            const h2 p12 = pk(wb1.x, wb1.y), p13 = pk(wb1.z, wb1.w);
#pragma unroll
            for (int n = 0; n < 10; ++n) {
                const H8 xv = *(const H8*)(XB + XO(n, cb + (c8 << 3)));
                a0[n] = dot2(xv.d, p03, dot2(xv.c, p02, dot2(xv.b, p01, dot2(xv.a, p00, a0[n]))));
                a1[n] = dot2(xv.d, p13, dot2(xv.c, p12, dot2(xv.b, p11, dot2(xv.a, p10, a1[n]))));
            }
        }
#pragma unroll
        for (int n = 0; n < 10; ++n) {
            SB[SO(n, o)]  = f16b(a0[n]);
            SB[SO(n, o2)] = f16b(a1[n]);
        }
    }
    __syncthreads();

    // ---- P3: shot = relu(S0 . A_sta + b_info), in place, 2 channels/thread ----
    {
        const int c0 = tl << 1;
        float sa[10], sb2[10];
#pragma unroll
        for (int n = 0; n < 10; ++n) {
            const h2 v = __builtin_bit_cast(h2, *(const unsigned int*)(SB + SO(n, c0)));
            sa[n] = (float)v[0]; sb2[n] = (float)v[1];
        }
        const float bi0 = b_info[c0], bi1 = b_info[c0 + 1];
        unsigned int o10[10];
#pragma unroll
        for (int m = 0; m < 10; ++m) {
            float t0 = bi0, t1 = bi1;
#pragma unroll
            for (int n = 0; n < 10; ++n) {
                const float a = SMf[ASTA + n * 10 + m];
                t0 += sa[n] * a; t1 += sb2[n] * a;
            }
            o10[m] = __builtin_bit_cast(unsigned int, pk(fmaxf(t0, 0.0f), fmaxf(t1, 0.0f)));
        }
#pragma unroll
        for (int m = 0; m < 10; ++m)
            *(unsigned int*)(SB + SO(m, c0)) = o10[m];
    }
    __syncthreads();

    // ---- P4: q_d/k_d (K=512, one output/thread) then q_s/k_s (K=64) ----
    {
        const int oc = tl & 127;
        const float* wr = ((tl < 128) ? wq_d : wk_d) + oc * 512;
        float acc[10];
#pragma unroll
        for (int n = 0; n < 10; ++n) acc[n] = 0.0f;
        for (int c8 = 0; c8 < 64; ++c8) {
            const float4 wa = *(const float4*)(wr + (c8 << 3));
            const float4 wb = *(const float4*)(wr + (c8 << 3) + 4);
            const h2 w0 = pk(wa.x, wa.y), w1 = pk(wa.z, wa.w);
            const h2 w2 = pk(wb.x, wb.y), w3 = pk(wb.z, wb.w);
#pragma unroll
            for (int n = 0; n < 10; ++n) {
                const H8 sv = *(const H8*)(SB + SO(n, c8 << 3));
                acc[n] = dot2(sv.d, w3, dot2(sv.c, w2, dot2(sv.b, w1, dot2(sv.a, w0, acc[n]))));
            }
        }
        unsigned short* dst = XB + ((tl < 128) ? QDT : KDT) + oc;
#pragma unroll
        for (int n = 0; n < 10; ++n) dst[n * 136] = f16b(acc[n]);
    }
    {
        const int oc = tl & 127;
        const int g = oc >> 4, cb = g << 6;
        const float* wr = ((tl < 128) ? wq_s : wk_s) + oc * 64;
        float acc[10];
#pragma unroll
        for (int n = 0; n < 10; ++n) acc[n] = 0.0f;
        for (int c8 = 0; c8 < 8; ++c8) {
            const float4 wa = *(const float4*)(wr + (c8 << 3));
            const float4 wb = *(const float4*)(wr + (c8 << 3) + 4);
            const h2 w0 = pk(wa.x, wa.y), w1 = pk(wa.z, wa.w);
            const h2 w2 = pk(wb.x, wb.y), w3 = pk(wb.z, wb.w);
#pragma unroll
            for (int n = 0; n < 10; ++n) {
                const H8 sv = *(const H8*)(SB + SO(n, cb + (c8 << 3)));
                acc[n] = dot2(sv.d, w3, dot2(sv.c, w2, dot2(sv.b, w1, dot2(sv.a, w0, acc[n]))));
            }
        }
        unsigned short* dst = XB + ((tl < 128) ? QST : KST) + oc;
#pragma unroll
        for (int n = 0; n < 10; ++n) dst[n * 136] = f16b(acc[n]);
    }
    __syncthreads();

    // ---- P5a: Bs logits ----
    if (tl < 100) {
        const int n = tl / 10, m = tl - (tl / 10) * 10;
        const unsigned short* q = XB + QST + n * 136;
        const unsigned short* k = XB + KST + m * 136;
        float s = 0.0f;
#pragma unroll
        for (int c8 = 0; c8 < 16; ++c8) {
            const H8 qv = *(const H8*)(q + (c8 << 3));
            const H8 kv = *(const H8*)(k + (c8 << 3));
            s = dot2(qv.d, kv.d, dot2(qv.c, kv.c, dot2(qv.b, kv.b, dot2(qv.a, kv.a, s))));
        }
        const int d = (n > m) ? (n - m) : (m - n);
        SMf[BSO + tl] = aS * (s * RSQRT128) + C_s[n * 10 + m] + ((d <= 3) ? 1.0f : 0.0f);
    }
    __syncthreads();

    // ---- P5b: Bd logits; softmax(As) ----
    if (tl < 100) {
        const int n = tl / 10, m = tl - (tl / 10) * 10;
        const unsigned short* q = XB + QDT + n * 136;
        const unsigned short* k = XB + KDT + m * 136;
        float s = 0.0f;
#pragma unroll
        for (int c8 = 0; c8 < 16; ++c8) {
            const H8 qv = *(const H8*)(q + (c8 << 3));
            const H8 kv = *(const H8*)(k + (c8 << 3));
            s = dot2(qv.d, kv.d, dot2(qv.c, kv.c, dot2(qv.b, kv.b, dot2(qv.a, kv.a, s))));
        }
        const int d = (n > m) ? (n - m) : (m - n);
        SMf[BDO + tl] = aD * (s * RSQRT128) + C_d[n * 10 + m] + ((d <= 3) ? 1.0f : 0.0f);
    } else if (tl >= 128 && tl < 138) {
        softmax10(SMf + BSO + (tl - 128) * 10);
    }
    __syncthreads();

    // ---- P6: Y0 = gconv(shot, w_sagg); PRD partials; softmax(Ad) ----
    {
        const int o = tl, g = o >> 5, cb = g << 6;
        const float* wr = w_sagg + o * 64;
        float acc[10];
#pragma unroll
        for (int n = 0; n < 10; ++n) acc[n] = 0.0f;
        for (int c8 = 0; c8 < 8; ++c8) {
            const float4 wa = *(const float4*)(wr + (c8 << 3));
            const float4 wb = *(const float4*)(wr + (c8 << 3) + 4);
            const h2 w0 = pk(wa.x, wa.y), w1 = pk(wa.z, wa.w);
            const h2 w2 = pk(wb.x, wb.y), w3 = pk(wb.z, wb.w);
#pragma unroll
            for (int n = 0; n < 10; ++n) {
                const H8 sv = *(const H8*)(SB + SO(n, cb + (c8 << 3)));
                acc[n] = dot2(sv.d, w3, dot2(sv.c, w2, dot2(sv.b, w1, dot2(sv.a, w0, acc[n]))));
            }
        }
        float* yr = XF + Y0F_BASE + o * 11;
#pragma unroll
        for (int n = 0; n < 10; ++n) yr[n] = acc[n];
    }
    for (int tt = tl; tt < 280; tt += 256) {
        const int o = tt / 40;
        const int rem = tt - o * 40;
        const int n = rem >> 2, part = rem & 3;
        const float* wr = w_dagg + o * 512 + (part << 7);
        float s = 0.0f;
#pragma unroll
        for (int j8 = 0; j8 < 16; ++j8) {
            const float4 wa = *(const float4*)(wr + (j8 << 3));
            const float4 wb = *(const float4*)(wr + (j8 << 3) + 4);
            const h2 w0 = pk(wa.x, wa.y), w1 = pk(wa.z, wa.w);
            const h2 w2 = pk(wb.x, wb.y), w3 = pk(wb.z, wb.w);
            const H8 sv = *(const H8*)(SB + SO(n, (part << 7) + (j8 << 3)));
            s = dot2(sv.d, w3, dot2(sv.c, w2, dot2(sv.b, w1, dot2(sv.a, w0, s))));
        }
        SMf[PRD + tt] = s;
    }
    if (tl >= 240 && tl < 250) softmax10(SMf + BDO + (tl - 240) * 10);
    __syncthreads();

    // ---- P7a: ys = relu(Y0 . As + b_sagg) in place; P0 finalize ----
    {
        const int o = tl;
        float* yr = XF + Y0F_BASE + o * 11;
        float r[10];
#pragma unroll
        for (int n = 0; n < 10; ++n) r[n] = yr[n];
        const float bs = b_sagg[o];
        float ys[10];
#pragma unroll
        for (int m = 0; m < 10; ++m) {
            float a = bs;
#pragma unroll
            for (int n = 0; n < 10; ++n) a += r[n] * SMf[BSO + n * 10 + m];
            ys[m] = fmaxf(a, 0.0f);
        }
#pragma unroll
        for (int m = 0; m < 10; ++m) yr[m] = ys[m];
    }
    if (tl < 70) {
        const int o = tl / 10, n = tl - (tl / 10) * 10;
        const float* pr = SMf + PRD + o * 40 + (n << 2);
        SMf[P0O + tl] = pr[0] + pr[1] + pr[2] + pr[3];
    }
    __syncthreads();

    // ---- P7b: T = S_d + alpha_diff * relu(P0 . Ad + b_dagg) ----
    if (tl < 70) {
        const int o = tl / 10, m = tl - (tl / 10) * 10;
        float a = b_dagg[o];
#pragma unroll
        for (int n = 0; n < 10; ++n) a += SMf[P0O + o * 10 + n] * SMf[BDO + n * 10 + m];
        SMf[TTO + tl] = S_d[o * 10 + m] + aDf * fmaxf(a, 0.0f);
    }
    __syncthreads();

    // ---- P8: scene[c][m] = sum_n ys[c][n] * T[m][n] ----
    {
        const int o = tl;
        const float* yr = XF + Y0F_BASE + o * 11;
        float r[10];
#pragma unroll
        for (int n = 0; n < 10; ++n) r[n] = yr[n];
#pragma unroll
        for (int m = 0; m < 7; ++m) {
            float a = 0.0f;
#pragma unroll
            for (int n = 0; n < 10; ++n) a += r[n] * SMf[TTO + m * 10 + n];
            XF[SCN_BASE + o * 7 + m] = a;
        }
    }
    __syncthreads();

    // ---- P9: v = relu(gconv(scene, w_mot, b_mot, g=8)) ----
    if (tl < 128) {
        const int o = tl;
        const int cb = (o >> 4) << 5;
        float wr[32];
#pragma unroll
        for (int i4 = 0; i4 < 8; ++i4) {
            const float4 w4 = *(const float4*)(w_mot + (o << 5) + (i4 << 2));
            wr[i4 * 4 + 0] = w4.x; wr[i4 * 4 + 1] = w4.y;
            wr[i4 * 4 + 2] = w4.z; wr[i4 * 4 + 3] = w4.w;
        }
        const float bm = b_mot[o];
#pragma unroll
        for (int s = 0; s < 7; ++s) {
            float a = bm;
#pragma unroll
            for (int i = 0; i < 32; ++i) a += wr[i] * XF[SCN_BASE + (cb + i) * 7 + s];
            XF[VV_BASE + o * 7 + s] = fmaxf(a, 0.0f);
        }
    }
    __syncthreads();

    // ---- P10: mu / logvar heads ----
    if (tl < 14) {
        const int hd = tl / 7;
        const int s = tl - hd * 7;
        const float* wp = hd ? w_logv : w_mean;
        float a = hd ? b_logv[0] : b_mean[0];
        for (int c = 0; c < 128; ++c) a += XF[VV_BASE + c * 7 + s] * wp[c];
        SMf[(hd ? LVO : MUO) + s] = a;
    }
    __syncthreads();

    // ---- P11: reparameterize + writes ----
    if (tl < 7) {
        const int s = tl;
        const float muv  = SMf[MUO + s];
        const float stdv = __expf(0.5f * SMf[LVO + s]);
        const float sc = muv + stdv * esp[b * 7 + s];
        SMf[SRO + s] = sc;
        out[(long)B + b * 7 + s]     = muv;
        out[(long)B * 8 + b * 7 + s] = stdv;
    }
    __syncthreads();
    if (tl == 0) {
        float s = 0.0f;
#pragma unroll
        for (int j = 0; j < 7; ++j) s += SMf[SRO + j];
        out[b] = s;
    }
}

extern "C" void kernel_launch(void* const* d_in, const int* in_sizes, int n_in,
                              void* d_out, int out_size, void* d_ws, size_t ws_size,
                              hipStream_t stream) {
    (void)n_in; (void)out_size; (void)d_ws; (void)ws_size;
    const int B = in_sizes[0] / 10240;
    if (B <= 0) return;
    dim3 grid(B), block(256);
    hgcn_fused<<<grid, block, 0, stream>>>(
        (const float*)d_in[0],  (const float*)d_in[1],  (const float*)d_in[2],
        (const float*)d_in[3],  (const float*)d_in[4],  (const float*)d_in[5],
        (const float*)d_in[6],  (const float*)d_in[7],  (const float*)d_in[8],
        (const float*)d_in[9],  (const float*)d_in[10], (const float*)d_in[11],
        (const float*)d_in[12], (const float*)d_in[13], (const float*)d_in[14],
        (const float*)d_in[15], (const float*)d_in[16], (const float*)d_in[17],
        (const float*)d_in[18], (const float*)d_in[19], (const float*)d_in[20],
        (const float*)d_in[21], (const float*)d_in[22], (const float*)d_in[23],
        (const float*)d_in[24], (const float*)d_in[25],
        (float*)d_out, B);
}

// Round 4
// 513.174 us; speedup vs baseline: 1.9451x; 1.1404x over previous
//
#include <hip/hip_runtime.h>

// f16 vector types
typedef _Float16 h2 __attribute__((ext_vector_type(2)));
typedef __fp16   h2n __attribute__((ext_vector_type(2)));   // builtin's native type
struct alignas(16) H8 { h2 a, b, c, d; };          // 8 halves = one b128
struct alignas(8)  U2 { unsigned int x, y; };      // one b64

static __device__ __forceinline__ float dot2(h2 a, h2 b, float c) {
#if __has_builtin(__builtin_amdgcn_fdot2)
    return __builtin_amdgcn_fdot2(__builtin_bit_cast(h2n, a),
                                  __builtin_bit_cast(h2n, b), c, false);
#else
    return c + (float)a[0] * (float)b[0] + (float)a[1] * (float)b[1];
#endif
}
static __device__ __forceinline__ float dot4(const H8& x, const H8& w, float c) {
    return dot2(x.d, w.d, dot2(x.c, w.c, dot2(x.b, w.b, dot2(x.a, w.a, c))));
}
static __device__ __forceinline__ h2 pk(float a, float b) {
#if __has_builtin(__builtin_amdgcn_cvt_pkrtz)
    return __builtin_bit_cast(h2, __builtin_amdgcn_cvt_pkrtz(a, b));
#else
    h2 r; r[0] = (_Float16)a; r[1] = (_Float16)b; return r;
#endif
}
static __device__ __forceinline__ unsigned short f16b(float v) {
    return __builtin_bit_cast(unsigned short, (_Float16)v);
}
static __device__ __forceinline__ float fast_tanh(float v) {
    return 1.0f - 2.0f / (__expf(2.0f * v) + 1.0f);
}
static __device__ __forceinline__ void softmax10(float* row) {
    float mx = row[0];
#pragma unroll
    for (int i = 1; i < 10; ++i) mx = fmaxf(mx, row[i]);
    float e[10]; float sm = 0.0f;
#pragma unroll
    for (int i = 0; i < 10; ++i) { e[i] = __expf(row[i] - mx); sm += e[i]; }
    const float inv = 1.0f / sm;
#pragma unroll
    for (int i = 0; i < 10; ++i) row[i] = e[i] * inv;
}

// ---- f16 weight cache (device global, rewritten every launch — deterministic)
#define WST 0          // w_state [256][128]
#define WIN 32768      // w_info  [512][128]
#define WQS 98304      // wq_s    [128][64]
#define WKS 106496     // wk_s    [128][64]
#define WSA 114688     // w_sagg  [256][64]
#define WQD 131072     // wq_d    [128][512]
#define WKD 196608     // wk_d    [128][512]
#define WDA 262144     // w_dagg  [7][512]
#define WTOT 265728
__device__ __align__(16) unsigned short W16[WTOT];

__global__ __launch_bounds__(256) void cvt_w(
        const float* __restrict__ ws,  const float* __restrict__ wi,
        const float* __restrict__ wqs, const float* __restrict__ wks,
        const float* __restrict__ wsa, const float* __restrict__ wqd,
        const float* __restrict__ wkd, const float* __restrict__ wda) {
    const int i2 = (blockIdx.x * 256 + threadIdx.x) * 2;
    if (i2 >= WTOT) return;
    const float* src; int off;
    if      (i2 < WIN) { src = ws;  off = WST; }
    else if (i2 < WQS) { src = wi;  off = WIN; }
    else if (i2 < WKS) { src = wqs; off = WQS; }
    else if (i2 < WSA) { src = wks; off = WKS; }
    else if (i2 < WQD) { src = wsa; off = WSA; }
    else if (i2 < WKD) { src = wqd; off = WQD; }
    else if (i2 < WDA) { src = wkd; off = WKD; }
    else               { src = wda; off = WDA; }
    const float a = src[i2 - off], b2 = src[i2 - off + 1];
    *(unsigned int*)(W16 + i2) = __builtin_bit_cast(unsigned int, pk(a, b2));
}

// LDS layouts (ushort offsets). Node-major f16 with per-group skew.
#define XO(n,c)  ((n)*1152 + (c) + (((c)>>6)<<3))   // x   [10][1024+skew]
#define SO(n,c)  ((n)*576  + (c) + (((c)>>6)<<3))   // shot[10][512+skew]

// qT tiles (f16) inside XB scratch (x dead after P1). Stride 136.
#define QST 0
#define KST 1360
#define QDT 2720
#define KDT 4080
// f32 views into XB scratch (XF = (float*)XB)
#define Y0F_BASE 2752      // Y0/ys [256][11]  (P6..P8)
#define SCN_BASE 0         // scene [256][7]   (P8..P9)
// SMf small f32 buffer
#define RED2 0             // tanh wave partials [4][17]
#define ASTA 68            // A_sta [10][10]
#define BSO  168           // Bs/As [10][10]
#define BDO  268           // Bd/Ad [10][10]
#define PRD  368           // w_dagg partials [280]
#define P0O  648           // P0 [7][10]
#define TTO  718           // T  [7][10]
#define MUO  788           // head partials [2 waves][14]
#define SMF_SZ 816

#define RSQRT128 0.08838834764831843f

__global__ __launch_bounds__(256, 4)
void hgcn_fused(const float* __restrict__ x,      const float* __restrict__ esp,
                const float* __restrict__ b_state,const float* __restrict__ b_info,
                const float* __restrict__ C_s,    const float* __restrict__ alpha_s,
                const float* __restrict__ b_sagg, const float* __restrict__ C_d,
                const float* __restrict__ alpha_d,const float* __restrict__ b_dagg,
                const float* __restrict__ S_d,    const float* __restrict__ alpha_dif,
                const float* __restrict__ w_mot,  const float* __restrict__ b_mot,
                const float* __restrict__ w_mean, const float* __restrict__ b_mean,
                const float* __restrict__ w_logv, const float* __restrict__ b_logv,
                float* __restrict__ out, int B)
{
    __shared__ __align__(16) unsigned short XB[11520];   // 23040 B
    __shared__ __align__(16) unsigned short SB[5760];    // 11520 B
    __shared__ __align__(16) float SMf[SMF_SZ];
    float* const XF = (float*)XB;

    const int tl = threadIdx.x;
    const long b = blockIdx.x;

    const float aS  = alpha_s[0];
    const float aD  = alpha_d[0];
    const float aDf = alpha_dif[0];

    // ---- P0: stage x[b] -> XB f16 node-major. Thread owns channels 4tl..4tl+3.
    {
        const float* xg = x + b * 10240 + tl * 40;
        float v[40];
#pragma unroll
        for (int k = 0; k < 10; ++k) {
            const float4 t = *(const float4*)(xg + (k << 2));
            v[k * 4 + 0] = t.x; v[k * 4 + 1] = t.y; v[k * 4 + 2] = t.z; v[k * 4 + 3] = t.w;
        }
#pragma unroll
        for (int n = 0; n < 10; ++n) {
            U2 u;
            u.x = __builtin_bit_cast(unsigned int, pk(v[n], v[10 + n]));
            u.y = __builtin_bit_cast(unsigned int, pk(v[20 + n], v[30 + n]));
            *(U2*)(XB + XO(n, tl << 2)) = u;
        }
    }
    __syncthreads();

    // ---- P1 (merged): state[tl] (regs) + info outs (g<<6)+li, +32 -> SB f16 ----
    {
        const int g = tl >> 5, li = tl & 31;
        const int cb = g << 7;
        const int oi0 = (g << 6) + li, oi1 = oi0 + 32;
        const unsigned short* wst = W16 + WST + tl  * 128;
        const unsigned short* wi0 = W16 + WIN + oi0 * 128;
        const unsigned short* wi1 = W16 + WIN + oi1 * 128;
        float as_[10], a0[10], a1[10];
#pragma unroll
        for (int n = 0; n < 10; ++n) { as_[n] = 0.0f; a0[n] = 0.0f; a1[n] = 0.0f; }
        for (int c8 = 0; c8 < 16; ++c8) {
            const H8 ws = *(const H8*)(wst + (c8 << 3));
            const H8 w0 = *(const H8*)(wi0 + (c8 << 3));
            const H8 w1 = *(const H8*)(wi1 + (c8 << 3));
#pragma unroll
            for (int n = 0; n < 10; ++n) {
                const H8 xv = *(const H8*)(XB + XO(n, cb + (c8 << 3)));
                as_[n] = dot4(xv, ws, as_[n]);
                a0[n]  = dot4(xv, w0, a0[n]);
                a1[n]  = dot4(xv, w1, a1[n]);
            }
        }
#pragma unroll
        for (int n = 0; n < 10; ++n) {
            SB[SO(n, oi0)] = f16b(a0[n]);
            SB[SO(n, oi1)] = f16b(a1[n]);
        }
        // state in regs (relu + bias)
        const float bb = b_state[tl];
        float st[10];
#pragma unroll
        for (int n = 0; n < 10; ++n) st[n] = fmaxf(as_[n] + bb, 0.0f);

        // ---- P2: tanh diffs, 17 pairs, block reduce via shfl butterfly ----
        float red[17];
#pragma unroll
        for (int p = 0; p < 17; ++p) {
            const int n = (p < 9) ? p : (p - 9);
            const int m = (p < 9) ? (p + 1) : (p - 9 + 2);
            red[p] = fast_tanh(st[n] - st[m]);
        }
#pragma unroll
        for (int stp = 1; stp < 64; stp <<= 1)
#pragma unroll
            for (int p = 0; p < 17; ++p) red[p] += __shfl_xor(red[p], stp);
        if ((tl & 63) == 0) {
            const int w = tl >> 6;
#pragma unroll
            for (int p = 0; p < 17; ++p) SMf[RED2 + w * 17 + p] = red[p];
        }
    }
    __syncthreads();

    // ---- P2b: assemble A_sta ----
    if (tl < 100) SMf[ASTA + tl] = 0.0f;
    __syncthreads();
    if (tl < 17) {
        const float s = (SMf[RED2 + tl] + SMf[RED2 + 17 + tl] +
                         SMf[RED2 + 34 + tl] + SMf[RED2 + 51 + tl]) * (1.0f / 256.0f);
        const int n = (tl < 9) ? tl : (tl - 9);
        const int m = (tl < 9) ? (tl + 1) : (tl - 9 + 2);
        SMf[ASTA + n * 10 + m] = s;
        SMf[ASTA + m * 10 + n] = -s;
    } else if (tl < 27) {
        const int n = tl - 17;
        SMf[ASTA + n * 10 + n] = 1.0f;
    }
    __syncthreads();

    // ---- P3: shot = relu(S0 . A_sta + b_info), in place, 2 channels/thread ----
    {
        const int c0 = tl << 1;
        float sa[10], sb2[10];
#pragma unroll
        for (int n = 0; n < 10; ++n) {
            const h2 v = __builtin_bit_cast(h2, *(const unsigned int*)(SB + SO(n, c0)));
            sa[n] = (float)v[0]; sb2[n] = (float)v[1];
        }
        const float bi0 = b_info[c0], bi1 = b_info[c0 + 1];
        unsigned int o10[10];
#pragma unroll
        for (int m = 0; m < 10; ++m) {
            float t0 = bi0, t1 = bi1;
#pragma unroll
            for (int n = 0; n < 10; ++n) {
                const float a = SMf[ASTA + n * 10 + m];
                t0 += sa[n] * a; t1 += sb2[n] * a;
            }
            o10[m] = __builtin_bit_cast(unsigned int, pk(fmaxf(t0, 0.0f), fmaxf(t1, 0.0f)));
        }
#pragma unroll
        for (int m = 0; m < 10; ++m)
            *(unsigned int*)(SB + SO(m, c0)) = o10[m];
    }
    __syncthreads();

    // ---- P4: q/k projections. K-split pairs: oc = tl>>1, kh = tl&1. ----
    {
        // dense d-branch: K=512, half = 256
        const int oc = tl >> 1, kh = tl & 1;
        const int cb = kh << 8;
        const unsigned short* wq = W16 + WQD + oc * 512 + cb;
        const unsigned short* wk = W16 + WKD + oc * 512 + cb;
        float aq[10], ak[10];
#pragma unroll
        for (int n = 0; n < 10; ++n) { aq[n] = 0.0f; ak[n] = 0.0f; }
        for (int c8 = 0; c8 < 32; ++c8) {
            const H8 wqv = *(const H8*)(wq + (c8 << 3));
            const H8 wkv = *(const H8*)(wk + (c8 << 3));
#pragma unroll
            for (int n = 0; n < 10; ++n) {
                const H8 sv = *(const H8*)(SB + SO(n, cb + (c8 << 3)));
                aq[n] = dot4(sv, wqv, aq[n]);
                ak[n] = dot4(sv, wkv, ak[n]);
            }
        }
#pragma unroll
        for (int n = 0; n < 10; ++n) {
            aq[n] += __shfl_xor(aq[n], 1);
            ak[n] += __shfl_xor(ak[n], 1);
        }
        unsigned short* dst = XB + (kh ? KDT : QDT) + oc;
        const float* src = kh ? ak : aq;
#pragma unroll
        for (int n = 0; n < 10; ++n) dst[n * 136] = f16b(src[n]);
    }
    {
        // grouped s-branch: K=64 per group, half = 32
        const int oc = tl >> 1, kh = tl & 1;
        const int g = oc >> 4;
        const int cb = (g << 6) + (kh << 5);
        const unsigned short* wq = W16 + WQS + oc * 64 + (kh << 5);
        const unsigned short* wk = W16 + WKS + oc * 64 + (kh << 5);
        float aq[10], ak[10];
#pragma unroll
        for (int n = 0; n < 10; ++n) { aq[n] = 0.0f; ak[n] = 0.0f; }
#pragma unroll
        for (int c8 = 0; c8 < 4; ++c8) {
            const H8 wqv = *(const H8*)(wq + (c8 << 3));
            const H8 wkv = *(const H8*)(wk + (c8 << 3));
#pragma unroll
            for (int n = 0; n < 10; ++n) {
                const H8 sv = *(const H8*)(SB + SO(n, cb + (c8 << 3)));
                aq[n] = dot4(sv, wqv, aq[n]);
                ak[n] = dot4(sv, wkv, ak[n]);
            }
        }
#pragma unroll
        for (int n = 0; n < 10; ++n) {
            aq[n] += __shfl_xor(aq[n], 1);
            ak[n] += __shfl_xor(ak[n], 1);
        }
        unsigned short* dst = XB + (kh ? KST : QST) + oc;
        const float* src = kh ? ak : aq;
#pragma unroll
        for (int n = 0; n < 10; ++n) dst[n * 136] = f16b(src[n]);
    }
    __syncthreads();

    // ---- P5: Bs logits (t<100) | Bd logits (100<=t<200) ----
    if (tl < 200) {
        const int t = (tl < 100) ? tl : (tl - 100);
        const int n = t / 10, m = t - (t / 10) * 10;
        const unsigned short* q = XB + ((tl < 100) ? QST : QDT) + n * 136;
        const unsigned short* k = XB + ((tl < 100) ? KST : KDT) + m * 136;
        float s = 0.0f;
#pragma unroll
        for (int c8 = 0; c8 < 16; ++c8) {
            const H8 qv = *(const H8*)(q + (c8 << 3));
            const H8 kv = *(const H8*)(k + (c8 << 3));
            s = dot4(qv, kv, s);
        }
        const int d = (n > m) ? (n - m) : (m - n);
        const float band = (d <= 3) ? 1.0f : 0.0f;
        if (tl < 100) SMf[BSO + t] = aS * (s * RSQRT128) + C_s[n * 10 + m] + band;
        else          SMf[BDO + t] = aD * (s * RSQRT128) + C_d[n * 10 + m] + band;
    }
    __syncthreads();

    // ---- P6: Y0 pairs + PRD partials + softmaxes ----
    {
        const int p = tl >> 1, kh = tl & 1;
        const int g = p >> 4, li = p & 15;
        const int o0 = (g << 5) + li, o1 = o0 + 16;
        const int cb = (g << 6) + (kh << 5);
        const unsigned short* w0 = W16 + WSA + o0 * 64 + (kh << 5);
        const unsigned short* w1 = W16 + WSA + o1 * 64 + (kh << 5);
        float a0[10], a1[10];
#pragma unroll
        for (int n = 0; n < 10; ++n) { a0[n] = 0.0f; a1[n] = 0.0f; }
#pragma unroll
        for (int c8 = 0; c8 < 4; ++c8) {
            const H8 wv0 = *(const H8*)(w0 + (c8 << 3));
            const H8 wv1 = *(const H8*)(w1 + (c8 << 3));
#pragma unroll
            for (int n = 0; n < 10; ++n) {
                const H8 sv = *(const H8*)(SB + SO(n, cb + (c8 << 3)));
                a0[n] = dot4(sv, wv0, a0[n]);
                a1[n] = dot4(sv, wv1, a1[n]);
            }
        }
#pragma unroll
        for (int n = 0; n < 10; ++n) {
            a0[n] += __shfl_xor(a0[n], 1);
            a1[n] += __shfl_xor(a1[n], 1);
        }
        float* yr = XF + Y0F_BASE + (kh ? o1 : o0) * 11;
        const float* src = kh ? a1 : a0;
#pragma unroll
        for (int n = 0; n < 10; ++n) yr[n] = src[n];
    }
    for (int tt = tl; tt < 280; tt += 256) {
        const int o = tt / 40;
        const int rem = tt - o * 40;
        const int n = rem >> 2, part = rem & 3;
        const unsigned short* wr = W16 + WDA + o * 512 + (part << 7);
        float s = 0.0f;
#pragma unroll
        for (int j8 = 0; j8 < 16; ++j8) {
            const H8 wv = *(const H8*)(wr + (j8 << 3));
            const H8 sv = *(const H8*)(SB + SO(n, (part << 7) + (j8 << 3)));
            s = dot4(sv, wv, s);
        }
        SMf[PRD + tt] = s;
    }
    if (tl >= 236 && tl < 246)      softmax10(SMf + BSO + (tl - 236) * 10);
    else if (tl >= 246)             softmax10(SMf + BDO + (tl - 246) * 10);
    __syncthreads();

    // ---- P7a: ys = relu(Y0 . As + b_sagg) in place; P0 finalize (70) ----
    {
        const int o = tl;
        float* yr = XF + Y0F_BASE + o * 11;
        float r[10];
#pragma unroll
        for (int n = 0; n < 10; ++n) r[n] = yr[n];
        const float bs = b_sagg[o];
        float ys[10];
#pragma unroll
        for (int m = 0; m < 10; ++m) {
            float a = bs;
#pragma unroll
            for (int n = 0; n < 10; ++n) a += r[n] * SMf[BSO + n * 10 + m];
            ys[m] = fmaxf(a, 0.0f);
        }
#pragma unroll
        for (int m = 0; m < 10; ++m) yr[m] = ys[m];
    }
    if (tl >= 186) {
        const int tt = tl - 186;
        const float* pr = SMf + PRD + (tt / 10) * 40 + ((tt - (tt / 10) * 10) << 2);
        SMf[P0O + tt] = pr[0] + pr[1] + pr[2] + pr[3];
    }
    __syncthreads();

    // ---- P7b: T = S_d + alpha_diff * relu(P0 . Ad + b_dagg) ----
    if (tl < 70) {
        const int o = tl / 10, m = tl - (tl / 10) * 10;
        float a = b_dagg[o];
#pragma unroll
        for (int n = 0; n < 10; ++n) a += SMf[P0O + o * 10 + n] * SMf[BDO + n * 10 + m];
        SMf[TTO + tl] = S_d[o * 10 + m] + aDf * fmaxf(a, 0.0f);
    }
    __syncthreads();

    // ---- P8: scene[c][m] = sum_n ys[c][n] * T[m][n] ----
    {
        const int o = tl;
        const float* yr = XF + Y0F_BASE + o * 11;
        float r[10];
#pragma unroll
        for (int n = 0; n < 10; ++n) r[n] = yr[n];
        float sc[7];
#pragma unroll
        for (int m = 0; m < 7; ++m) {
            float a = 0.0f;
#pragma unroll
            for (int n = 0; n < 10; ++n) a += r[n] * SMf[TTO + m * 10 + n];
            sc[m] = a;
        }
        __syncthreads();   // Y0 reads done; SCN aliases qT region (dead)
#pragma unroll
        for (int m = 0; m < 7; ++m) XF[SCN_BASE + o * 7 + m] = sc[m];
    }
    __syncthreads();

    // ---- P9+P10: v = relu(gconv(scene, w_mot)) fused with head partials ----
    if (tl < 128) {
        const int o = tl;
        const int cb = (o >> 4) << 5;
        float wr[32];
#pragma unroll
        for (int i4 = 0; i4 < 8; ++i4) {
            const float4 w4 = *(const float4*)(w_mot + (o << 5) + (i4 << 2));
            wr[i4 * 4 + 0] = w4.x; wr[i4 * 4 + 1] = w4.y;
            wr[i4 * 4 + 2] = w4.z; wr[i4 * 4 + 3] = w4.w;
        }
        const float bm = b_mot[o];
        const float wm = w_mean[o], wl = w_logv[o];
        float mu_p[7], lv_p[7];
#pragma unroll
        for (int s = 0; s < 7; ++s) {
            float a = bm;
#pragma unroll
            for (int i = 0; i < 32; ++i) a += wr[i] * XF[SCN_BASE + (cb + i) * 7 + s];
            const float v = fmaxf(a, 0.0f);
            mu_p[s] = v * wm; lv_p[s] = v * wl;
        }
#pragma unroll
        for (int stp = 1; stp < 64; stp <<= 1)
#pragma unroll
            for (int s = 0; s < 7; ++s) {
                mu_p[s] += __shfl_xor(mu_p[s], stp);
                lv_p[s] += __shfl_xor(lv_p[s], stp);
            }
        if ((tl & 63) == 0) {
            const int w = tl >> 6;
#pragma unroll
            for (int s = 0; s < 7; ++s) {
                SMf[MUO + w * 14 + s]     = mu_p[s];
                SMf[MUO + w * 14 + 7 + s] = lv_p[s];
            }
        }
    }
    __syncthreads();

    // ---- P11: reparameterize + writes (no further barrier) ----
    if (tl < 64) {
        float sc = 0.0f;
        if (tl < 7) {
            const float mu = b_mean[0] + SMf[MUO + tl] + SMf[MUO + 14 + tl];
            const float lv = b_logv[0] + SMf[MUO + 7 + tl] + SMf[MUO + 21 + tl];
            const float sd = __expf(0.5f * lv);
            sc = mu + sd * esp[b * 7 + tl];
            out[(long)B + b * 7 + tl]     = mu;
            out[(long)B * 8 + b * 7 + tl] = sd;
        }
#pragma unroll
        for (int stp = 1; stp < 8; stp <<= 1) sc += __shfl_xor(sc, stp);
        if (tl == 0) out[b] = sc;
    }
}

extern "C" void kernel_launch(void* const* d_in, const int* in_sizes, int n_in,
                              void* d_out, int out_size, void* d_ws, size_t ws_size,
                              hipStream_t stream) {
    (void)n_in; (void)out_size; (void)d_ws; (void)ws_size;
    const int B = in_sizes[0] / 10240;
    if (B <= 0) return;

    cvt_w<<<dim3((WTOT / 2 + 255) / 256), dim3(256), 0, stream>>>(
        (const float*)d_in[2],  (const float*)d_in[4],  (const float*)d_in[6],
        (const float*)d_in[7],  (const float*)d_in[10], (const float*)d_in[12],
        (const float*)d_in[13], (const float*)d_in[16]);

    hgcn_fused<<<dim3(B), dim3(256), 0, stream>>>(
        (const float*)d_in[0],  (const float*)d_in[1],  (const float*)d_in[3],
        (const float*)d_in[5],  (const float*)d_in[8],  (const float*)d_in[9],
        (const float*)d_in[11], (const float*)d_in[14], (const float*)d_in[15],
        (const float*)d_in[17], (const float*)d_in[18], (const float*)d_in[19],
        (const float*)d_in[20], (const float*)d_in[21], (const float*)d_in[22],
        (const float*)d_in[23], (const float*)d_in[24], (const float*)d_in[25],
        (float*)d_out, B);
}